// Round 6
// baseline (424.684 us; speedup 1.0000x reference)
//
#include <hip/hip_runtime.h>
#include <cmath>

#define HDIM 2048
#define NEXP 16
#define IDIM 512
#define ISDIM 2048
#define NTOK 2048
#define MAXT 48                 // 128-row expert tiles: 4096/128 + 16
#define ROWSCAP (MAXT * 128)    // 6144

#define GU_EXP (MAXT * 4)                    // 192 (IDIM/128 = 4 n-tiles)
#define GU_SH ((NTOK / 128) * (ISDIM / 128)) // 256
#define DN_SH ((NTOK / 128) * (HDIM / 256))  // 128
#define DN_EXP (MAXT * 8)                    // 384 (HDIM/256 = 8 n-tiles)

typedef short bf16x8 __attribute__((ext_vector_type(8)));
typedef float f32x4 __attribute__((ext_vector_type(4)));
typedef unsigned short us;
typedef __attribute__((address_space(1))) const unsigned int* as1p;
typedef __attribute__((address_space(3))) unsigned int* as3p;

__device__ __forceinline__ us f2bf(float f) {
  unsigned int u = __builtin_bit_cast(unsigned int, f);
  u += 0x7FFFu + ((u >> 16) & 1u);
  return (us)(u >> 16);
}
__device__ __forceinline__ float bf2f(us v) {
  return __builtin_bit_cast(float, (unsigned)v << 16);
}

// async 16B/lane global->LDS; global vaddr per-lane, LDS base wave-uniform
__device__ __forceinline__ void glds16(const void* g, void* l) {
  __builtin_amdgcn_global_load_lds((as1p)(unsigned long long)g,
                                   (as3p)(unsigned int)(unsigned long long)l, 16, 0, 0);
}

// load 8 fp32 (cacheable; L3 retains across iterations), round-half-up to
// bf16 (same arithmetic as all prior passing rounds), 16B cacheable store.
__device__ __forceinline__ void cvt8(const float* __restrict__ src,
                                     us* __restrict__ dst) {
  const float4* p = (const float4*)src;
  float4 a = p[0], b = p[1];
  unsigned u0 = __builtin_bit_cast(unsigned, a.x) + 0x8000u;
  unsigned u1 = __builtin_bit_cast(unsigned, a.y) + 0x8000u;
  unsigned u2 = __builtin_bit_cast(unsigned, a.z) + 0x8000u;
  unsigned u3 = __builtin_bit_cast(unsigned, a.w) + 0x8000u;
  unsigned u4 = __builtin_bit_cast(unsigned, b.x) + 0x8000u;
  unsigned u5 = __builtin_bit_cast(unsigned, b.y) + 0x8000u;
  unsigned u6 = __builtin_bit_cast(unsigned, b.z) + 0x8000u;
  unsigned u7 = __builtin_bit_cast(unsigned, b.w) + 0x8000u;
  int4 v;
  v.x = __builtin_amdgcn_perm(u1, u0, 0x07060302);
  v.y = __builtin_amdgcn_perm(u3, u2, 0x07060302);
  v.z = __builtin_amdgcn_perm(u5, u4, 0x07060302);
  v.w = __builtin_amdgcn_perm(u7, u6, 0x07060302);
  *(int4*)dst = v;
}

// ------- kernel 1: fused router + x->bf16 + weight fp32->bf16 convert -----
// Block = one token. Router: 4 waves x H/4 slice, 17 interleaved acc chains,
// butterfly + LDS cross-wave reduce (latency-bound, ~3% BW). Convert: each
// block streams a 3840-unit (30720-float) weight slice (BW-bound). Fused so
// the router stalls hide under the convert stream.
__global__ __launch_bounds__(256) void k_front(
    const float* __restrict__ x, const float* __restrict__ gate_w,
    const float* __restrict__ sgw, const float* __restrict__ w1,
    const float* __restrict__ w2, const float* __restrict__ w3,
    const float* __restrict__ wsg, const float* __restrict__ wsu,
    const float* __restrict__ wsd, us* __restrict__ xb,
    us* __restrict__ w1b, us* __restrict__ w2b, us* __restrict__ w3b,
    us* __restrict__ wsgb, us* __restrict__ wsub, us* __restrict__ wsdb,
    int* __restrict__ sel, float* __restrict__ wnorm,
    float* __restrict__ sig, int* __restrict__ counts) {
  __shared__ float lg[4][17];
  __shared__ float L[17];
  int tid = threadIdx.x, wid = tid >> 6, lane = tid & 63;
  int t = blockIdx.x;
  // ---- router part (identical numerics to round-5 k_router) ----
  const float4* xrow = reinterpret_cast<const float4*>(x + (size_t)t * HDIM);
  int i0 = wid * 128 + lane;
  float4 xv0 = xrow[i0], xv1 = xrow[i0 + 64];
  ushort4* xbrow = reinterpret_cast<ushort4*>(xb + (size_t)t * HDIM);
  ushort4 o0, o1;
  o0.x = f2bf(xv0.x); o0.y = f2bf(xv0.y); o0.z = f2bf(xv0.z); o0.w = f2bf(xv0.w);
  o1.x = f2bf(xv1.x); o1.y = f2bf(xv1.y); o1.z = f2bf(xv1.z); o1.w = f2bf(xv1.w);
  xbrow[i0] = o0;
  xbrow[i0 + 64] = o1;
  float acc[17];
#pragma unroll
  for (int e = 0; e < 17; e++) acc[e] = 0.f;
#pragma unroll
  for (int e = 0; e < 17; e++) {
    const float4* gr =
        reinterpret_cast<const float4*>(e < 16 ? gate_w + (size_t)e * HDIM : sgw);
    float4 g0 = gr[i0], g1 = gr[i0 + 64];
    acc[e] += xv0.x * g0.x + xv0.y * g0.y + xv0.z * g0.z + xv0.w * g0.w +
              xv1.x * g1.x + xv1.y * g1.y + xv1.z * g1.z + xv1.w * g1.w;
  }
#pragma unroll
  for (int off = 32; off; off >>= 1) {
#pragma unroll
    for (int e = 0; e < 17; e++) acc[e] += __shfl_xor(acc[e], off, 64);
  }
  if (lane == 0) {
#pragma unroll
    for (int e = 0; e < 17; e++) lg[wid][e] = acc[e];
  }
  __syncthreads();
  if (tid < 17) L[tid] = lg[0][tid] + lg[1][tid] + lg[2][tid] + lg[3][tid];
  __syncthreads();
  if (tid == 0) {
    int i1 = 0; float v1 = L[0];
#pragma unroll
    for (int i = 1; i < NEXP; i++) if (L[i] > v1) { v1 = L[i]; i1 = i; }
    int i2 = (i1 == 0) ? 1 : 0; float v2 = L[i2];
#pragma unroll
    for (int i = 0; i < NEXP; i++)
      if (i != i1 && i != i2 && L[i] > v2) { v2 = L[i]; i2 = i; }
    float wa = 1.f / (1.f + expf(v2 - v1));  // renorm top-2 softmax
    sel[2 * t] = i1; sel[2 * t + 1] = i2;
    wnorm[2 * t] = wa; wnorm[2 * t + 1] = 1.f - wa;
    sig[t] = 1.f / (1.f + expf(-L[16]));
    atomicAdd(&counts[i1], 1);
    atomicAdd(&counts[i2], 1);
  }
  // ---- convert part: 3840 8-float units per block, 15 per thread ----
  // unit boundaries (in 8-float units):
  const size_t U1 = 2097152, U2 = 4194304, U3 = 6291456,
               U4 = 6815744, U5 = 7340032;
  size_t u0 = (size_t)blockIdx.x * 3840 + tid;
#pragma unroll
  for (int j = 0; j < 15; j++) {
    size_t u = u0 + (size_t)j * 256;
    const float* s; us* d; size_t off;
    if (u < U1)      { s = w1;  d = w1b;  off = u; }
    else if (u < U2) { s = w2;  d = w2b;  off = u - U1; }
    else if (u < U3) { s = w3;  d = w3b;  off = u - U2; }
    else if (u < U4) { s = wsg; d = wsgb; off = u - U3; }
    else if (u < U5) { s = wsu; d = wsub; off = u - U4; }
    else             { s = wsd; d = wsdb; off = u - U5; }
    cvt8(s + off * 8, d + off * 8);
  }
}

// ------- kernel 2: per-expert ballot-compaction scatter (16 blocks) -------
__global__ __launch_bounds__(64) void k_scatter(const int* __restrict__ counts,
                                                const int* __restrict__ sel,
                                                const float* __restrict__ wnorm,
                                                int* __restrict__ tile_expert,
                                                int* __restrict__ row_token,
                                                int* __restrict__ rowk,
                                                float* __restrict__ rw) {
  int e = blockIdx.x, lane = threadIdx.x;
  int base = 0, total = 0, nt_e = 0, cnt_e = 0;
  for (int i = 0; i < NEXP; i++) {
    int c = counts[i];
    int nt = (c + 127) >> 7;
    if (i == e) { base = total; cnt_e = c; nt_e = nt; }
    total += nt << 7;
  }
  for (int i = lane; i < nt_e; i += 64) tile_expert[(base >> 7) + i] = e;
  if (e == NEXP - 1)
    for (int m = (total >> 7) + lane; m < MAXT; m += 64) tile_expert[m] = -1;
  for (int r = cnt_e + lane; r < nt_e * 128; r += 64) row_token[base + r] = -1;
  int run = 0;
  for (int t0 = 0; t0 < NTOK; t0 += 64) {
    int t = t0 + lane;
    int s0 = sel[2 * t], s1 = sel[2 * t + 1];
    int k = (s1 == e) ? 1 : 0;
    bool m = (s0 == e) || (s1 == e);
    unsigned long long mask = __ballot(m);
    int rank = __popcll(mask & ((1ull << lane) - 1ull));
    if (m) {
      int row = base + run + rank;
      row_token[row] = t;
      rowk[row] = k;
      rw[row] = wnorm[2 * t + k];
    }
    run += __popcll(mask);
  }
}

// ------- kernel 3: gate/up GEMM, 128x128 tiles, 512 thr, all-bf16 ---------
// waves 0-3: G matrix (2x2 of 64x64), waves 4-7: U. Epilogue joins via LDS.
// A and B both staged via global_load_lds w=16 with pre-swizzled global src.
__global__ __launch_bounds__(512) void k_gu(
    const us* __restrict__ xb, const us* __restrict__ w1b,
    const us* __restrict__ w3b, const us* __restrict__ wsgb,
    const us* __restrict__ wsub, const int* __restrict__ tile_expert,
    const int* __restrict__ row_token, us* __restrict__ hmid,
    us* __restrict__ hs) {
  __shared__ us As[128 * 64];      // 16KB
  __shared__ us Bs[2][128 * 64];   // 32KB (G,U); reused as 128x128 U-buf in epilogue
  __shared__ int toks_s[128];
  int bid = blockIdx.x, tid = threadIdx.x;
  int w = tid >> 6, lane = tid & 63;
  const us *bG, *bU;
  us* outp;
  int mt, n0, ostride;
  if (bid < GU_EXP) {
    mt = bid >> 2; int nt = bid & 3;
    int e = tile_expert[mt];
    if (e < 0) return;
    if (tid < 128) {
      int tk = row_token[mt * 128 + tid];
      toks_s[tid] = tk < 0 ? 0 : tk;
    }
    bG = w1b + ((size_t)e * IDIM + nt * 128) * HDIM;
    bU = w3b + ((size_t)e * IDIM + nt * 128) * HDIM;
    outp = hmid; ostride = IDIM; n0 = nt * 128;
  } else {
    int sb = bid - GU_EXP;
    mt = sb >> 4; int nt = sb & 15;
    if (tid < 128) toks_s[tid] = mt * 128 + tid;
    bG = wsgb + (size_t)(nt * 128) * HDIM;
    bU = wsub + (size_t)(nt * 128) * HDIM;
    outp = hs; ostride = ISDIM; n0 = nt * 128;
  }
  __syncthreads();
  int lr = lane >> 3, lc = lane & 7;
  int swz = (lc ^ lr) * 8;
  const us* aSrc0 = xb + (size_t)toks_s[w * 16 + lr] * HDIM + swz;
  const us* aSrc1 = xb + (size_t)toks_s[w * 16 + 8 + lr] * HDIM + swz;
  int mat = w >> 2, sub = w & 3, wm = sub >> 1, wn = sub & 1;
  // wave (mat,sub) stages B rows [sub*32, sub*32+32) of its own matrix
  const us* bSrc = (mat ? bU : bG) + (size_t)(sub * 32 + lr) * HDIM + swz;
  us* bDst = &Bs[mat][sub * 32 * 64];
  int quad = lane >> 4, l16 = lane & 15, sw = l16 & 7;
  f32x4 acc[4][4] = {};
  for (int k0 = 0; k0 < HDIM; k0 += 64) {
    glds16(aSrc0 + k0, As + w * 1024);
    glds16(aSrc1 + k0, As + w * 1024 + 512);
#pragma unroll
    for (int g = 0; g < 4; g++)
      glds16(bSrc + (size_t)(g * 8) * HDIM + k0, bDst + g * 512);
    __syncthreads();
#pragma unroll
    for (int ks = 0; ks < 2; ks++) {
      int cb = (ks * 4 + quad) ^ sw;
      bf16x8 af[4], bf[4];
#pragma unroll
      for (int ms = 0; ms < 4; ms++)
        af[ms] = *(const bf16x8*)&As[((wm * 64 + ms * 16 + l16) * 8 + cb) * 8];
#pragma unroll
      for (int ns = 0; ns < 4; ns++)
        bf[ns] = *(const bf16x8*)&Bs[mat][((wn * 64 + ns * 16 + l16) * 8 + cb) * 8];
#pragma unroll
      for (int ms = 0; ms < 4; ms++)
#pragma unroll
        for (int ns = 0; ns < 4; ns++)
          acc[ms][ns] = __builtin_amdgcn_mfma_f32_16x16x32_bf16(af[ms], bf[ns], acc[ms][ns], 0, 0, 0);
    }
    __syncthreads();
  }
  // epilogue: U waves park u (bf16) in LDS; G waves do silu(g)*u -> store
  us* ub = (us*)Bs;
  if (mat == 1) {
#pragma unroll
    for (int ms = 0; ms < 4; ms++)
#pragma unroll
      for (int ns = 0; ns < 4; ns++)
#pragma unroll
        for (int r = 0; r < 4; r++) {
          int row = wm * 64 + ms * 16 + quad * 4 + r;
          int col = wn * 64 + ns * 16 + l16;
          ub[row * 128 + col] = f2bf(acc[ms][ns][r]);
        }
  }
  __syncthreads();
  if (mat == 0) {
#pragma unroll
    for (int ms = 0; ms < 4; ms++)
#pragma unroll
      for (int ns = 0; ns < 4; ns++)
#pragma unroll
        for (int r = 0; r < 4; r++) {
          int row = wm * 64 + ms * 16 + quad * 4 + r;
          int col = wn * 64 + ns * 16 + l16;
          float g = acc[ms][ns][r];
          float u = bf2f(ub[row * 128 + col]);
          float hv = (g / (1.f + __expf(-g))) * u;
          outp[(size_t)(mt * 128 + row) * ostride + n0 + col] = f2bf(hv);
        }
  }
}

// ------- kernel 4: down GEMMs 128x256, all-bf16, weighted stores ----------
__global__ __launch_bounds__(512) void k_down(
    const us* __restrict__ hmid, const us* __restrict__ hs,
    const us* __restrict__ w2b, const us* __restrict__ wsdb,
    const int* __restrict__ tile_expert, const int* __restrict__ row_token,
    const int* __restrict__ rowk, const float* __restrict__ rw,
    const float* __restrict__ sig, us* __restrict__ slab) {
  __shared__ us As[128 * 64];   // 16KB
  __shared__ us Bs[256 * 64];   // 32KB
  __shared__ int idx_s[128];
  __shared__ float wgt_s[128];
  int bid = blockIdx.x, tid = threadIdx.x;
  int w = tid >> 6, lane = tid & 63;
  const us* aBase;
  const us* bBase;
  int K, mt, n0;
  if (bid < DN_SH) {  // shared expert first (K=2048, longest)
    mt = bid >> 3; int nt = bid & 7;
    aBase = hs + (size_t)mt * 128 * ISDIM; K = ISDIM;
    bBase = wsdb + (size_t)(nt * 256) * ISDIM;
    n0 = nt * 256;
    if (tid < 128) {
      int t = mt * 128 + tid;
      idx_s[tid] = 2 * NTOK * HDIM + t * HDIM;
      wgt_s[tid] = sig[t];
    }
  } else {
    int sb = bid - DN_SH;
    mt = sb >> 3; int nt = sb & 7;
    int e = tile_expert[mt];
    if (e < 0) return;
    aBase = hmid + (size_t)mt * 128 * IDIM; K = IDIM;
    bBase = w2b + ((size_t)e * HDIM + nt * 256) * IDIM;
    n0 = nt * 256;
    if (tid < 128) {
      int tk = row_token[mt * 128 + tid];
      if (tk < 0) { idx_s[tid] = -1; wgt_s[tid] = 0.f; }
      else {
        idx_s[tid] = (rowk[mt * 128 + tid] * NTOK + tk) * HDIM;
        wgt_s[tid] = rw[mt * 128 + tid];
      }
    }
  }
  __syncthreads();
  int lr = lane >> 3, lc = lane & 7;
  int swz = (lc ^ lr) * 8;
  const us* aSrc0 = aBase + (size_t)(w * 16 + lr) * K + swz;
  const us* aSrc1 = aBase + (size_t)(w * 16 + 8 + lr) * K + swz;
  // wave w stages B rows [w*32, w*32+32)
  const us* bSrc = bBase + (size_t)(w * 32 + lr) * K + swz;
  us* bDst = Bs + w * 32 * 64;
  int wmn = w >> 2, wn = w & 3;  // waves 2(m) x 4(n)
  int quad = lane >> 4, l16 = lane & 15, sw = l16 & 7;
  f32x4 acc[4][4] = {};
  for (int k0 = 0; k0 < K; k0 += 64) {
    glds16(aSrc0 + k0, As + w * 1024);
    glds16(aSrc1 + k0, As + w * 1024 + 512);
#pragma unroll
    for (int g = 0; g < 4; g++)
      glds16(bSrc + (size_t)(g * 8) * K + k0, bDst + g * 512);
    __syncthreads();
#pragma unroll
    for (int ks = 0; ks < 2; ks++) {
      int cb = (ks * 4 + quad) ^ sw;
      bf16x8 af[4], bf[4];
#pragma unroll
      for (int ms = 0; ms < 4; ms++)
        af[ms] = *(const bf16x8*)&As[((wmn * 64 + ms * 16 + l16) * 8 + cb) * 8];
#pragma unroll
      for (int ns = 0; ns < 4; ns++)
        bf[ns] = *(const bf16x8*)&Bs[((wn * 64 + ns * 16 + l16) * 8 + cb) * 8];
#pragma unroll
      for (int ms = 0; ms < 4; ms++)
#pragma unroll
        for (int ns = 0; ns < 4; ns++)
          acc[ms][ns] = __builtin_amdgcn_mfma_f32_16x16x32_bf16(af[ms], bf[ns], acc[ms][ns], 0, 0, 0);
    }
    __syncthreads();
  }
#pragma unroll
  for (int ms = 0; ms < 4; ms++)
#pragma unroll
    for (int r = 0; r < 4; r++) {
      int rr = wmn * 64 + ms * 16 + quad * 4 + r;
      int ix = idx_s[rr];
      if (ix >= 0) {
        float wgt = wgt_s[rr];
        us* orow = slab + (size_t)ix + n0 + wn * 64;
#pragma unroll
        for (int ns = 0; ns < 4; ns++)
          orow[ns * 16 + l16] = f2bf(wgt * acc[ms][ns][r]);
      }
    }
}

// ------- kernel 5: out = slot0 + slot1 + shared (streaming, nt) -----------
__global__ __launch_bounds__(256) void k_combine(const us* __restrict__ slab,
                                                 float* __restrict__ out) {
  size_t i = ((size_t)blockIdx.x * 256 + threadIdx.x) * 8;
  bf16x8 a = __builtin_nontemporal_load((const bf16x8*)(slab + i));
  bf16x8 b = __builtin_nontemporal_load((const bf16x8*)(slab + (size_t)NTOK * HDIM + i));
  bf16x8 c = __builtin_nontemporal_load((const bf16x8*)(slab + 2 * (size_t)NTOK * HDIM + i));
  f32x4 o0, o1;
#pragma unroll
  for (int j = 0; j < 4; j++)
    o0[j] = bf2f((us)a[j]) + bf2f((us)b[j]) + bf2f((us)c[j]);
#pragma unroll
  for (int j = 0; j < 4; j++)
    o1[j] = bf2f((us)a[4 + j]) + bf2f((us)b[4 + j]) + bf2f((us)c[4 + j]);
  __builtin_nontemporal_store(o0, (f32x4*)(out + i));
  __builtin_nontemporal_store(o1, (f32x4*)(out + i + 4));
}

extern "C" void kernel_launch(void* const* d_in, const int* in_sizes, int n_in,
                              void* d_out, int out_size, void* d_ws, size_t ws_size,
                              hipStream_t stream) {
  const float* x = (const float*)d_in[0];
  const float* gate_w = (const float*)d_in[1];
  const float* w1 = (const float*)d_in[2];
  const float* w2 = (const float*)d_in[3];
  const float* w3 = (const float*)d_in[4];
  const float* wsg = (const float*)d_in[5];
  const float* wsu = (const float*)d_in[6];
  const float* wsd = (const float*)d_in[7];
  const float* sgw = (const float*)d_in[8];
  float* out = (float*)d_out;

  // workspace carve (16B aligned)
  us* xb = (us*)d_ws;                               // NTOK*HDIM
  us* hs = xb + (size_t)NTOK * HDIM;                // NTOK*ISDIM
  us* hmid = hs + (size_t)NTOK * ISDIM;             // ROWSCAP*IDIM
  us* slab = hmid + (size_t)ROWSCAP * IDIM;         // 3*NTOK*HDIM
  us* w1b = slab + (size_t)3 * NTOK * HDIM;         // E*I*H
  us* w3b = w1b + (size_t)NEXP * IDIM * HDIM;       // E*I*H
  us* w2b = w3b + (size_t)NEXP * IDIM * HDIM;       // E*H*I
  us* wsgb = w2b + (size_t)NEXP * HDIM * IDIM;      // IS*H
  us* wsub = wsgb + (size_t)ISDIM * HDIM;           // IS*H
  us* wsdb = wsub + (size_t)ISDIM * HDIM;           // H*IS
  float* rw = (float*)(wsdb + (size_t)HDIM * ISDIM);  // ROWSCAP
  float* wnorm = rw + ROWSCAP;                      // 4096
  float* sig = wnorm + 2 * NTOK;                    // 2048
  int* sel = (int*)(sig + NTOK);                    // 4096
  int* row_token = sel + 2 * NTOK;                  // ROWSCAP
  int* rowk = row_token + ROWSCAP;                  // ROWSCAP
  int* counts = rowk + ROWSCAP;                     // 16
  int* tile_expert = counts + NEXP;                 // MAXT

  hipMemsetAsync(counts, 0, NEXP * sizeof(int), stream);
  k_front<<<dim3(NTOK), dim3(256), 0, stream>>>(
      x, gate_w, sgw, w1, w2, w3, wsg, wsu, wsd, xb,
      w1b, w2b, w3b, wsgb, wsub, wsdb, sel, wnorm, sig, counts);
  k_scatter<<<dim3(NEXP), dim3(64), 0, stream>>>(counts, sel, wnorm, tile_expert,
                                                 row_token, rowk, rw);
  k_gu<<<dim3(GU_EXP + GU_SH), dim3(512), 0, stream>>>(
      xb, w1b, w3b, wsgb, wsub, tile_expert, row_token, hmid, hs);
  k_down<<<dim3(DN_SH + DN_EXP), dim3(512), 0, stream>>>(
      hmid, hs, w2b, wsdb, tile_expert, row_token, rowk, rw, sig, slab);
  k_combine<<<dim3(NTOK * HDIM / 2048), dim3(256), 0, stream>>>(slab, out);
}